// Round 1
// baseline (732.150 us; speedup 1.0000x reference)
//
#include <hip/hip_runtime.h>
#include <hip/hip_bf16.h>

typedef unsigned short u16;
typedef __attribute__((ext_vector_type(8))) short bf16x8;
typedef __attribute__((ext_vector_type(4))) float f32x4;

#define BB 16
#define CCH 512
#define HW 4096
#define PP 1024

__device__ __forceinline__ u16 f2bf(float f) {
  union { float f; unsigned u; } v; v.f = f;
  unsigned r = v.u + 0x7fffu + ((v.u >> 16) & 1u);
  return (u16)(r >> 16);
}
__device__ __forceinline__ float bf2f(u16 h) {
  union { unsigned u; float f; } v; v.u = ((unsigned)h) << 16;
  return v.f;
}

// ---------------- pool: x -> Fb (bf16 pooled), Xb (bf16 copy of x), xmean ---
__global__ __launch_bounds__(256) void pool_kernel(
    const float* __restrict__ x, u16* __restrict__ Fb, u16* __restrict__ Xb,
    float* __restrict__ xmean) {
  int bc = blockIdx.x;  // b*512 + c
  const float2* xr = (const float2*)(x + (size_t)bc * HW);
  ushort2* xb2 = (ushort2*)(Xb + (size_t)bc * HW);
  u16* fb = Fb + (size_t)bc * PP;
  int t = threadIdx.x;
  float sum = 0.f;
#pragma unroll
  for (int s = 0; s < 4; ++s) {
    int p = t + s * 256;            // pooled index 0..1023
    int py = p >> 5, px = p & 31;
    float2 a = xr[py * 64 + px];        // row 2py, cols 2px,2px+1
    float2 b = xr[py * 64 + 32 + px];   // row 2py+1
    float pooled = 0.25f * (a.x + a.y + b.x + b.y);
    fb[p] = f2bf(pooled);
    sum += pooled;
    ushort2 ua; ua.x = f2bf(a.x); ua.y = f2bf(a.y);
    ushort2 ub; ub.x = f2bf(b.x); ub.y = f2bf(b.y);
    xb2[py * 64 + px] = ua;
    xb2[py * 64 + 32 + px] = ub;
  }
#pragma unroll
  for (int o = 32; o; o >>= 1) sum += __shfl_xor(sum, o);
  __shared__ float red[4];
  if ((t & 63) == 0) red[t >> 6] = sum;
  __syncthreads();
  if (t == 0) xmean[bc] = (red[0] + red[1] + red[2] + red[3]) * (1.0f / 1024.0f);
}

// ---------------- transpose bf16 [R][C] -> [C][R], 64x64 tiles --------------
__global__ __launch_bounds__(256) void transpose_bf16(
    const u16* __restrict__ in, u16* __restrict__ out, int R, int C) {
  __shared__ u16 t[64][65];
  size_t bo = (size_t)blockIdx.z * R * C;
  int tr = blockIdx.y * 64, tc = blockIdx.x * 64;
  int tid = threadIdx.x;
#pragma unroll
  for (int s = 0; s < 2; ++s) {
    int i = tid + s * 256;
    int r = i >> 3, c8 = (i & 7) * 8;
    bf16x8 v = *(const bf16x8*)&in[bo + (size_t)(tr + r) * C + tc + c8];
#pragma unroll
    for (int j = 0; j < 8; ++j) t[r][c8 + j] = (u16)v[j];
  }
  __syncthreads();
#pragma unroll
  for (int s = 0; s < 2; ++s) {
    int i = tid + s * 256;
    int n = i >> 3, k8 = (i & 7) * 8;
    bf16x8 o;
#pragma unroll
    for (int j = 0; j < 8; ++j) o[j] = (short)t[k8 + j][n];
    *(bf16x8*)&out[bo + (size_t)(tc + n) * R + tr + k8] = o;
  }
}

// ---------------- softmax over rows of G (in-place), also S1b = Sc - I ------
__global__ void softmax_rows(float* __restrict__ G, u16* __restrict__ S1b) {
  size_t row = blockIdx.x;  // b*512 + c
  float* g = G + row * 512;
  int lane = threadIdx.x;   // 64
  float v[8];
  float mx = -3.4e38f;
#pragma unroll
  for (int i = 0; i < 8; ++i) { v[i] = g[lane + i * 64]; mx = fmaxf(mx, v[i]); }
#pragma unroll
  for (int o = 32; o; o >>= 1) mx = fmaxf(mx, __shfl_xor(mx, o));
  float s = 0.f;
#pragma unroll
  for (int i = 0; i < 8; ++i) { v[i] = expf(v[i] - mx); s += v[i]; }
#pragma unroll
  for (int o = 32; o; o >>= 1) s += __shfl_xor(s, o);
  float inv = 1.0f / s;
  int c = (int)(row & 511);
#pragma unroll
  for (int i = 0; i < 8; ++i) {
    int d = lane + i * 64;
    float sc = v[i] * inv;
    g[d] = sc;
    S1b[row * 512 + d] = f2bf(sc - (d == c ? 1.0f : 0.0f));
  }
}

// ---------------- bilinear 2x upsample (half-pixel, edge-renorm) + mean -----
__global__ __launch_bounds__(256) void upsample_kernel(
    const u16* __restrict__ Mcb, u16* __restrict__ Mup, float* __restrict__ mmean) {
  __shared__ float lm[1024];
  __shared__ float red[4];
  size_t bd = blockIdx.x;  // b*512 + d
  const u16* src = Mcb + bd * 1024;
  u16* dst = Mup + bd * 4096;
  int tid = threadIdx.x;
  for (int i = tid; i < 1024; i += 256) lm[i] = bf2f(src[i]);
  __syncthreads();
  float sum = 0.f;
#pragma unroll
  for (int it = 0; it < 16; ++it) {
    int idx = it * 256 + tid;
    int oy = idx >> 6, ox = idx & 63;
    int jy = oy >> 1, jx = ox >> 1;
    int y0, y1; float wy0;
    if (oy & 1) { y0 = jy; y1 = (jy < 31) ? jy + 1 : 31; wy0 = 0.75f; }
    else        { y0 = (jy > 0) ? jy - 1 : 0; y1 = jy; wy0 = (oy == 0) ? 0.0f : 0.25f; }
    int x0, x1; float wx0;
    if (ox & 1) { x0 = jx; x1 = (jx < 31) ? jx + 1 : 31; wx0 = 0.75f; }
    else        { x0 = (jx > 0) ? jx - 1 : 0; x1 = jx; wx0 = (ox == 0) ? 0.0f : 0.25f; }
    float wy1 = 1.0f - wy0, wx1 = 1.0f - wx0;
    float v = wy0 * (wx0 * lm[y0 * 32 + x0] + wx1 * lm[y0 * 32 + x1])
            + wy1 * (wx0 * lm[y1 * 32 + x0] + wx1 * lm[y1 * 32 + x1]);
    sum += v;
    dst[idx] = f2bf(v);
  }
#pragma unroll
  for (int o = 32; o; o >>= 1) sum += __shfl_xor(sum, o);
  if ((tid & 63) == 0) red[tid >> 6] = sum;
  __syncthreads();
  if (tid == 0) mmean[bd] = (red[0] + red[1] + red[2] + red[3]) * (1.0f / 4096.0f);
}

// ---------------- NT bf16 GEMM, 128x128 tile, BK=32, 4 waves ----------------
// C[m][n] = sum_k A[m][k]*B[n][k]  (both row-major along K), fp32 accum.
// MODE 0: G store fp32.  MODE 1: Mc = acc + F (bf16 out).
// MODE 2: cov = acc/4096 - xm*mm (fp32 out) ; L1 = Sc + cov - I (bf16 out).
// MODE 3: Ec = acc + x (fp32 out).
template <int MODE>
__global__ __launch_bounds__(256) void gemm_nt(
    const u16* __restrict__ A, const u16* __restrict__ B, int K, int lda, int ldb,
    size_t aStride, size_t bStride,
    float* __restrict__ outF, u16* __restrict__ outB,
    const u16* __restrict__ addB, const float* __restrict__ addF,
    const float* __restrict__ scp, const float* __restrict__ xm,
    const float* __restrict__ mm, int ldo, size_t oStride) {
  __shared__ u16 As[128 * 32];
  __shared__ u16 Bs[128 * 32];
  const int tid = threadIdx.x;
  const int lane = tid & 63, wave = tid >> 6;
  const int wr = wave >> 1, wc = wave & 1;
  const int z = blockIdx.z;
  const u16* Ab = A + (size_t)z * aStride + (size_t)(blockIdx.y * 128) * lda;
  const u16* Bb = B + (size_t)z * bStride + (size_t)(blockIdx.x * 128) * ldb;

  f32x4 acc[4][4] = {};

  const int r0 = tid >> 2;          // 0..63
  const int ko0 = (tid & 3) * 8;
  const int fr = lane & 15, kq = lane >> 4;

  for (int k0 = 0; k0 < K; k0 += 32) {
    __syncthreads();
#pragma unroll
    for (int s = 0; s < 2; ++s) {
      int row = r0 + s * 64;
      *(bf16x8*)&As[row * 32 + ko0] = *(const bf16x8*)&Ab[(size_t)row * lda + k0 + ko0];
      *(bf16x8*)&Bs[row * 32 + ko0] = *(const bf16x8*)&Bb[(size_t)row * ldb + k0 + ko0];
    }
    __syncthreads();
    bf16x8 af[4], bfr[4];
#pragma unroll
    for (int m = 0; m < 4; ++m)
      af[m] = *(const bf16x8*)&As[(wr * 64 + m * 16 + fr) * 32 + kq * 8];
#pragma unroll
    for (int n = 0; n < 4; ++n)
      bfr[n] = *(const bf16x8*)&Bs[(wc * 64 + n * 16 + fr) * 32 + kq * 8];
#pragma unroll
    for (int m = 0; m < 4; ++m)
#pragma unroll
      for (int n = 0; n < 4; ++n)
        acc[m][n] = __builtin_amdgcn_mfma_f32_16x16x32_bf16(af[m], bfr[n], acc[m][n], 0, 0, 0);
  }

  const int cq = lane >> 4, cr = lane & 15;
#pragma unroll
  for (int m = 0; m < 4; ++m) {
#pragma unroll
    for (int n = 0; n < 4; ++n) {
      int row0 = blockIdx.y * 128 + wr * 64 + m * 16 + cq * 4;
      int col  = blockIdx.x * 128 + wc * 64 + n * 16 + cr;
#pragma unroll
      for (int j = 0; j < 4; ++j) {
        int r = row0 + j;
        float val = acc[m][n][j];
        size_t idx = oStride * (size_t)z + (size_t)r * ldo + col;
        if constexpr (MODE == 0) {
          outF[idx] = val;
        } else if constexpr (MODE == 1) {
          outB[idx] = f2bf(val + bf2f(addB[idx]));
        } else if constexpr (MODE == 2) {
          float cv = val * (1.0f / 4096.0f) - xm[z * CCH + r] * mm[z * CCH + col];
          outF[idx] = cv;
          float l1 = scp[idx] + cv - (r == col ? 1.0f : 0.0f);
          outB[idx] = f2bf(l1);
        } else {
          outF[idx] = val + addF[idx];
        }
      }
    }
  }
}

// ---------------- out = x * (beta*Ec + x) ----------------------------------
__global__ void finalize_kernel(const float* __restrict__ x, const float* __restrict__ ec,
                                const float* __restrict__ beta, float* __restrict__ out) {
  float b = beta[0];
  size_t i = (size_t)blockIdx.x * 256 + threadIdx.x;
  size_t stride = (size_t)gridDim.x * 256;
  const float4* x4 = (const float4*)x;
  const float4* e4 = (const float4*)ec;
  float4* o4 = (float4*)out;
  size_t n4 = (size_t)BB * CCH * HW / 4;
  for (size_t p = i; p < n4; p += stride) {
    float4 xv = x4[p], ev = e4[p];
    float4 ov;
    ov.x = xv.x * (b * ev.x + xv.x);
    ov.y = xv.y * (b * ev.y + xv.y);
    ov.z = xv.z * (b * ev.z + xv.z);
    ov.w = xv.w * (b * ev.w + xv.w);
    o4[p] = ov;
  }
}

extern "C" void kernel_launch(void* const* d_in, const int* in_sizes, int n_in,
                              void* d_out, int out_size, void* d_ws, size_t ws_size,
                              hipStream_t stream) {
  const float* x = (const float*)d_in[0];
  const float* beta = (const float*)d_in[1];

  const size_t NX = (size_t)BB * CCH * HW;       // 33,554,432
  const size_t NCOV = (size_t)BB * CCH * CCH;    // 4,194,304

  float* out_f = (float*)d_out;
  float* cov_f = out_f + NX;
  float* sc_f  = cov_f + NCOV;
  float* ec_f  = sc_f + NCOV;

  // scratch aliased into d_out (dead before the slot's real write):
  u16* XbT = (u16*)d_out;            // [b][4096][512] bf16, first half of out-slot
  u16* Mup = (u16*)d_out + NX;       // [b][512][4096] bf16, second half of out-slot
  u16* Xb  = (u16*)ec_f;             // [b][512][4096] bf16, first half of Ec-slot

  char* w = (char*)d_ws;
  u16* Fb   = (u16*)(w);                    // [b][512][1024] bf16
  u16* FbT  = (u16*)(w + 16777216);         // [b][1024][512]
  u16* Mcb  = (u16*)(w + 33554432);         // [b][512][1024]
  u16* S1b  = (u16*)(w + 50331648);         // [b][512][512]  (Sc - I)
  u16* L1b  = (u16*)(w + 58720256);         // [b][512][512]  (Lc - I)
  float* xmean = (float*)(w + 67108864);    // [b][512]
  float* mmean = (float*)(w + 67141632);    // [b][512]

  // 1. pool + bf16 copy of x + per-channel mean of x
  pool_kernel<<<BB * CCH, 256, 0, stream>>>(x, Fb, Xb, xmean);
  // 2. F^T  (per batch 512x1024 -> 1024x512)
  transpose_bf16<<<dim3(16, 8, BB), 256, 0, stream>>>(Fb, FbT, 512, 1024);
  // 3. X^T  (per batch 512x4096 -> 4096x512)
  transpose_bf16<<<dim3(64, 8, BB), 256, 0, stream>>>(Xb, XbT, 512, 4096);
  // 4. Gram G = F F^T -> Sc slot (fp32)
  gemm_nt<0><<<dim3(4, 4, BB), 256, 0, stream>>>(
      Fb, Fb, 1024, 1024, 1024, (size_t)CCH * PP, (size_t)CCH * PP,
      sc_f, nullptr, nullptr, nullptr, nullptr, nullptr, nullptr, 512, NCOV / BB);
  // 5. softmax rows (in place) + S1 = Sc - I (bf16)
  softmax_rows<<<BB * CCH, 64, 0, stream>>>(sc_f, S1b);
  // 6. Mc = S1 @ F + F  (bf16)
  gemm_nt<1><<<dim3(8, 4, BB), 256, 0, stream>>>(
      S1b, FbT, 512, 512, 512, (size_t)CCH * CCH, (size_t)PP * CCH,
      nullptr, Mcb, Fb, nullptr, nullptr, nullptr, nullptr, 1024, (size_t)CCH * PP);
  // 7. upsample Mc -> Mup (bf16) + per-channel mean
  upsample_kernel<<<BB * CCH, 256, 0, stream>>>(Mcb, Mup, mmean);
  // 8. cov = Xb Mup^T / 4096 - xm mm^T  -> cov slot; L1 = Sc + cov - I (bf16)
  gemm_nt<2><<<dim3(4, 4, BB), 256, 0, stream>>>(
      Xb, Mup, 4096, 4096, 4096, NX / BB, NX / BB,
      cov_f, L1b, nullptr, nullptr, sc_f, xmean, mmean, 512, NCOV / BB);
  // 9. Ec = L1 @ X + x  -> Ec slot (fp32); overwrites Xb region (dead)
  gemm_nt<3><<<dim3(32, 4, BB), 256, 0, stream>>>(
      L1b, XbT, 512, 512, 512, (size_t)CCH * CCH, NX / BB,
      ec_f, nullptr, nullptr, x, nullptr, nullptr, nullptr, 4096, NX / BB);
  // 10. out = x * (beta*Ec + x); overwrites XbT/Mup (dead)
  finalize_kernel<<<4096, 256, 0, stream>>>(x, ec_f, beta, out_f);
}

// Round 2
// 698.441 us; speedup vs baseline: 1.0483x; 1.0483x over previous
//
#include <hip/hip_runtime.h>
#include <hip/hip_bf16.h>

typedef unsigned short u16;
typedef __attribute__((ext_vector_type(8))) short bf16x8;
typedef __attribute__((ext_vector_type(4))) float f32x4;

#define BB 16
#define CCH 512
#define HW 4096
#define PP 1024

__device__ __forceinline__ u16 f2bf(float f) {
  union { float f; unsigned u; } v; v.f = f;
  unsigned r = v.u + 0x7fffu + ((v.u >> 16) & 1u);
  return (u16)(r >> 16);
}
__device__ __forceinline__ float bf2f(u16 h) {
  union { unsigned u; float f; } v; v.u = ((unsigned)h) << 16;
  return v.f;
}

typedef __attribute__((address_space(1))) const unsigned gas_u32;
typedef __attribute__((address_space(3))) unsigned las_u32;
__device__ __forceinline__ void gl_lds16(const u16* g, u16* l) {
  // 16B per lane, dest = wave-uniform base + lane*16 (linear)
  __builtin_amdgcn_global_load_lds((gas_u32*)g, (las_u32*)l, 16, 0, 0);
}

// ---------------- pool: x -> Fb (bf16 pooled), Xb (bf16 copy of x), xmean ---
__global__ __launch_bounds__(256) void pool_kernel(
    const float* __restrict__ x, u16* __restrict__ Fb, u16* __restrict__ Xb,
    float* __restrict__ xmean) {
  int bc = blockIdx.x;  // b*512 + c
  const float4* xr4 = (const float4*)(x + (size_t)bc * HW);
  ushort4* xb4 = (ushort4*)(Xb + (size_t)bc * HW);
  ushort2* fb2 = (ushort2*)(Fb + (size_t)bc * PP);
  int t = threadIdx.x;
  float sum = 0.f;
#pragma unroll
  for (int s = 0; s < 2; ++s) {
    int i = s * 256 + t;           // pooled-pair index 0..511
    int py = i >> 4, pxq = i & 15; // pooled row, float4 col index
    float4 a = xr4[(2 * py) * 16 + pxq];
    float4 b = xr4[(2 * py + 1) * 16 + pxq];
    float p0 = 0.25f * (a.x + a.y + b.x + b.y);
    float p1 = 0.25f * (a.z + a.w + b.z + b.w);
    ushort2 fp; fp.x = f2bf(p0); fp.y = f2bf(p1);
    fb2[i] = fp;
    sum += p0 + p1;
    ushort4 ua; ua.x = f2bf(a.x); ua.y = f2bf(a.y); ua.z = f2bf(a.z); ua.w = f2bf(a.w);
    ushort4 ub; ub.x = f2bf(b.x); ub.y = f2bf(b.y); ub.z = f2bf(b.z); ub.w = f2bf(b.w);
    xb4[(2 * py) * 16 + pxq] = ua;
    xb4[(2 * py + 1) * 16 + pxq] = ub;
  }
#pragma unroll
  for (int o = 32; o; o >>= 1) sum += __shfl_xor(sum, o);
  __shared__ float red[4];
  if ((t & 63) == 0) red[t >> 6] = sum;
  __syncthreads();
  if (t == 0) xmean[bc] = (red[0] + red[1] + red[2] + red[3]) * (1.0f / 1024.0f);
}

// ---------------- transpose bf16 [R][C] -> [C][R], 64x64 tiles --------------
__global__ __launch_bounds__(256) void transpose_bf16(
    const u16* __restrict__ in, u16* __restrict__ out, int R, int C) {
  __shared__ u16 t[64][65];
  size_t bo = (size_t)blockIdx.z * R * C;
  int tr = blockIdx.y * 64, tc = blockIdx.x * 64;
  int tid = threadIdx.x;
#pragma unroll
  for (int s = 0; s < 2; ++s) {
    int i = tid + s * 256;
    int r = i >> 3, c8 = (i & 7) * 8;
    bf16x8 v = *(const bf16x8*)&in[bo + (size_t)(tr + r) * C + tc + c8];
#pragma unroll
    for (int j = 0; j < 8; ++j) t[r][c8 + j] = (u16)v[j];
  }
  __syncthreads();
#pragma unroll
  for (int s = 0; s < 2; ++s) {
    int i = tid + s * 256;
    int n = i >> 3, k8 = (i & 7) * 8;
    bf16x8 o;
#pragma unroll
    for (int j = 0; j < 8; ++j) o[j] = (short)t[k8 + j][n];
    *(bf16x8*)&out[bo + (size_t)(tc + n) * R + tr + k8] = o;
  }
}

// --------- softmax over rows; input = 2 gram partials; out Sc + (Sc-I) bf16 -
__global__ void softmax_rows(const float* __restrict__ P, float* __restrict__ Sc,
                             u16* __restrict__ S1b) {
  size_t row = blockIdx.x;  // b*512 + c
  int z = (int)(row >> 9);
  const float* p0 = P + ((size_t)z * 2) * 262144 + (size_t)(row & 511) * 512;
  const float* p1 = p0 + 262144;
  float* g = Sc + row * 512;
  int lane = threadIdx.x;  // 64
  float v[8];
  float mx = -3.4e38f;
#pragma unroll
  for (int i = 0; i < 8; ++i) {
    int d = lane + i * 64;
    v[i] = p0[d] + p1[d];
    mx = fmaxf(mx, v[i]);
  }
#pragma unroll
  for (int o = 32; o; o >>= 1) mx = fmaxf(mx, __shfl_xor(mx, o));
  float s = 0.f;
#pragma unroll
  for (int i = 0; i < 8; ++i) { v[i] = expf(v[i] - mx); s += v[i]; }
#pragma unroll
  for (int o = 32; o; o >>= 1) s += __shfl_xor(s, o);
  float inv = 1.0f / s;
  int c = (int)(row & 511);
#pragma unroll
  for (int i = 0; i < 8; ++i) {
    int d = lane + i * 64;
    float sc = v[i] * inv;
    g[d] = sc;
    S1b[row * 512 + d] = f2bf(sc - (d == c ? 1.0f : 0.0f));
  }
}

// ---------------- bilinear 2x upsample (half-pixel, edge clamp) + mean ------
__global__ __launch_bounds__(256) void upsample_kernel(
    const u16* __restrict__ Mcb, u16* __restrict__ Mup, float* __restrict__ mmean) {
  __shared__ float lm[1024];
  __shared__ float red[4];
  size_t bd = blockIdx.x;  // b*512 + d
  const u16* src = Mcb + bd * 1024;
  u16* dst = Mup + bd * 4096;
  int tid = threadIdx.x;
  for (int i = tid; i < 1024; i += 256) lm[i] = bf2f(src[i]);
  __syncthreads();
  float sum = 0.f;
#pragma unroll
  for (int it = 0; it < 16; ++it) {
    int idx = it * 256 + tid;
    int oy = idx >> 6, ox = idx & 63;
    int jy = oy >> 1, jx = ox >> 1;
    int y0, y1; float wy0;
    if (oy & 1) { y0 = jy; y1 = (jy < 31) ? jy + 1 : 31; wy0 = 0.75f; }
    else        { y0 = (jy > 0) ? jy - 1 : 0; y1 = jy; wy0 = (oy == 0) ? 0.0f : 0.25f; }
    int x0, x1; float wx0;
    if (ox & 1) { x0 = jx; x1 = (jx < 31) ? jx + 1 : 31; wx0 = 0.75f; }
    else        { x0 = (jx > 0) ? jx - 1 : 0; x1 = jx; wx0 = (ox == 0) ? 0.0f : 0.25f; }
    float wy1 = 1.0f - wy0, wx1 = 1.0f - wx0;
    float v = wy0 * (wx0 * lm[y0 * 32 + x0] + wx1 * lm[y0 * 32 + x1])
            + wy1 * (wx0 * lm[y1 * 32 + x0] + wx1 * lm[y1 * 32 + x1]);
    sum += v;
    dst[idx] = f2bf(v);
  }
#pragma unroll
  for (int o = 32; o; o >>= 1) sum += __shfl_xor(sum, o);
  if ((tid & 63) == 0) red[tid >> 6] = sum;
  __syncthreads();
  if (tid == 0) mmean[bd] = (red[0] + red[1] + red[2] + red[3]) * (1.0f / 4096.0f);
}

// ---------------- NT bf16 GEMM, 128x128 tile, BK=32, 4 waves, gload_lds -----
// C[m][n] = sum_k A[m][k]*B[n][k], fp32 accum. LOGSPLIT: split-K folded into
// blockIdx.z (z = batch<<LOGSPLIT | split); partial outputs indexed by raw z.
// MODE 0: partial fp32 store. MODE 1: Mc = acc + F (bf16).
// MODE 3: Ec = acc + x (fp32). MODE 4: ec = acc + x; out = x*(beta*ec+x).
template <int MODE, int LOGSPLIT>
__global__ __launch_bounds__(256) void gemm_nt(
    const u16* __restrict__ A, const u16* __restrict__ B, int K, int lda, int ldb,
    size_t aStride, size_t bStride,
    float* __restrict__ outF, float* __restrict__ out2F, u16* __restrict__ outB,
    const u16* __restrict__ addB, const float* __restrict__ addF,
    const float* __restrict__ bp, int ldo, size_t oStride) {
  __shared__ u16 As[128 * 32];
  __shared__ u16 Bs[128 * 32];
  const int tid = threadIdx.x;
  const int lane = tid & 63, wave = tid >> 6;
  const int wr = wave >> 1, wc = wave & 1;
  const int zi = blockIdx.z;
  const int sp = zi & ((1 << LOGSPLIT) - 1);
  const int z = zi >> LOGSPLIT;
  const u16* Ab = A + (size_t)z * aStride + (size_t)sp * K + (size_t)(blockIdx.y * 128) * lda;
  const u16* Bb = B + (size_t)z * bStride + (size_t)sp * K + (size_t)(blockIdx.x * 128) * ldb;

  f32x4 acc[4][4] = {};

  // staging map: wave w pass p covers rows [(w+4p)*16, +16); lane -> row l>>2, col (l&3)*8
  const int stRow = lane >> 2;
  const int stCol = (lane & 3) * 8;
  u16* aL0 = As + (wave * 16) * 32;
  u16* aL1 = As + ((wave + 4) * 16) * 32;
  u16* bL0 = Bs + (wave * 16) * 32;
  u16* bL1 = Bs + ((wave + 4) * 16) * 32;
  const int fr = lane & 15, kq = lane >> 4;

  for (int k0 = 0; k0 < K; k0 += 32) {
    __syncthreads();
    gl_lds16(Ab + (size_t)(wave * 16 + stRow) * lda + k0 + stCol, aL0);
    gl_lds16(Ab + (size_t)((wave + 4) * 16 + stRow) * lda + k0 + stCol, aL1);
    gl_lds16(Bb + (size_t)(wave * 16 + stRow) * ldb + k0 + stCol, bL0);
    gl_lds16(Bb + (size_t)((wave + 4) * 16 + stRow) * ldb + k0 + stCol, bL1);
    __syncthreads();
    bf16x8 af[4], bfr[4];
#pragma unroll
    for (int m = 0; m < 4; ++m)
      af[m] = *(const bf16x8*)&As[(wr * 64 + m * 16 + fr) * 32 + kq * 8];
#pragma unroll
    for (int n = 0; n < 4; ++n)
      bfr[n] = *(const bf16x8*)&Bs[(wc * 64 + n * 16 + fr) * 32 + kq * 8];
#pragma unroll
    for (int m = 0; m < 4; ++m)
#pragma unroll
      for (int n = 0; n < 4; ++n)
        acc[m][n] = __builtin_amdgcn_mfma_f32_16x16x32_bf16(af[m], bfr[n], acc[m][n], 0, 0, 0);
  }

  float betaV = 0.f;
  if constexpr (MODE == 4) betaV = bp[0];
  const int cq = lane >> 4, cr = lane & 15;
#pragma unroll
  for (int m = 0; m < 4; ++m) {
#pragma unroll
    for (int n = 0; n < 4; ++n) {
      int row0 = blockIdx.y * 128 + wr * 64 + m * 16 + cq * 4;
      int col  = blockIdx.x * 128 + wc * 64 + n * 16 + cr;
#pragma unroll
      for (int j = 0; j < 4; ++j) {
        int r = row0 + j;
        float val = acc[m][n][j];
        size_t idx = oStride * (size_t)zi + (size_t)r * ldo + col;
        if constexpr (MODE == 0) {
          outF[idx] = val;
        } else if constexpr (MODE == 1) {
          outB[idx] = f2bf(val + bf2f(addB[idx]));
        } else if constexpr (MODE == 3) {
          outF[idx] = val + addF[idx];
        } else if constexpr (MODE == 4) {
          float xv = addF[idx];
          float ec = val + xv;
          outF[idx] = ec;
          out2F[idx] = xv * (betaV * ec + xv);
        }
      }
    }
  }
}

// ---------------- combine: cov = sum(parts)/4096 - xm*mm ; L1 = Sc+cov-I ----
__global__ __launch_bounds__(256) void combine_cov(
    const float* __restrict__ parts, const float* __restrict__ sc,
    const float* __restrict__ xm, const float* __restrict__ mm,
    float* __restrict__ cov, u16* __restrict__ L1b) {
  int row = blockIdx.x;  // z*512 + r
  int z = row >> 9, r = row & 511;
  size_t base = (size_t)z * 262144 + (size_t)r * 512;
  size_t pz = (size_t)z * 4 * 262144 + (size_t)r * 512;
  float xmr = xm[row];
#pragma unroll
  for (int j = 0; j < 2; ++j) {
    int c = threadIdx.x + j * 256;
    float s = parts[pz + c] + parts[pz + 262144 + c] +
              parts[pz + 2 * 262144 + c] + parts[pz + 3 * 262144 + c];
    float cv = s * (1.0f / 4096.0f) - xmr * mm[z * 512 + c];
    cov[base + c] = cv;
    L1b[base + c] = f2bf(sc[base + c] + cv - (r == c ? 1.0f : 0.0f));
  }
}

// ---------------- out = x * (beta*Ec + x)  (fallback path only) -------------
__global__ void finalize_kernel(const float* __restrict__ x, const float* __restrict__ ec,
                                const float* __restrict__ beta, float* __restrict__ out) {
  float b = beta[0];
  size_t i = (size_t)blockIdx.x * 256 + threadIdx.x;
  size_t stride = (size_t)gridDim.x * 256;
  const float4* x4 = (const float4*)x;
  const float4* e4 = (const float4*)ec;
  float4* o4 = (float4*)out;
  size_t n4 = (size_t)BB * CCH * HW / 4;
  for (size_t p = i; p < n4; p += stride) {
    float4 xv = x4[p], ev = e4[p];
    float4 ov;
    ov.x = xv.x * (b * ev.x + xv.x);
    ov.y = xv.y * (b * ev.y + xv.y);
    ov.z = xv.z * (b * ev.z + xv.z);
    ov.w = xv.w * (b * ev.w + xv.w);
    o4[p] = ov;
  }
}

extern "C" void kernel_launch(void* const* d_in, const int* in_sizes, int n_in,
                              void* d_out, int out_size, void* d_ws, size_t ws_size,
                              hipStream_t stream) {
  const float* x = (const float*)d_in[0];
  const float* beta = (const float*)d_in[1];

  const size_t NX = (size_t)BB * CCH * HW;     // 33,554,432
  const size_t NCOV = (size_t)BB * CCH * CCH;  // 4,194,304

  float* out_f = (float*)d_out;
  float* cov_f = out_f + NX;
  float* sc_f  = cov_f + NCOV;
  float* ec_f  = sc_f + NCOV;

  // ec-slot aliases (bytes): first half Xb (bf16), second half fp32 spare.
  u16* Xb = (u16*)ec_f;               // [b][512][4096] bf16 (dead after cov GEMM)
  float* spare = ec_f + NX / 2;       // 16,777,216 floats (gram + cov partials)

  char* w = (char*)d_ws;
  u16* Fb   = (u16*)(w);                   // [b][512][1024]
  u16* FbT  = (u16*)(w + 16777216);        // [b][1024][512]
  u16* Mcb  = (u16*)(w + 33554432);        // [b][512][1024]
  u16* S1b  = (u16*)(w + 50331648);        // [b][512][512]  Sc - I
  u16* L1b  = (u16*)(w + 58720256);        // [b][512][512]  Lc - I
  float* xmean = (float*)(w + 67108864);   // [b][512]
  float* mmean = (float*)(w + 67141632);   // [b][512]
  const size_t WS_BASE = 67174400;         // 64M + 64K
  const bool bigws = ws_size >= WS_BASE + (size_t)134217728;  // + 64MB XbT

  // XbT: ws if it fits (enables fused finalize), else out-slot first half.
  u16* XbT = bigws ? (u16*)(w + WS_BASE) : (u16*)d_out;
  // Mup always in out-slot second half (dead before out is written).
  u16* Mup = (u16*)d_out + NX;

  // 1. pool + bf16 copy of x + per-channel mean
  pool_kernel<<<BB * CCH, 256, 0, stream>>>(x, Fb, Xb, xmean);
  // 2. F^T (512x1024 -> 1024x512 per batch)
  transpose_bf16<<<dim3(16, 8, BB), 256, 0, stream>>>(Fb, FbT, 512, 1024);
  // 3. X^T (512x4096 -> 4096x512 per batch)
  transpose_bf16<<<dim3(64, 8, BB), 256, 0, stream>>>(Xb, XbT, 512, 4096);
  // 4. Gram G = F F^T, split-K x2 in one dispatch -> spare partials
  gemm_nt<0, 1><<<dim3(4, 4, BB * 2), 256, 0, stream>>>(
      Fb, Fb, 512, 1024, 1024, (size_t)CCH * PP, (size_t)CCH * PP,
      spare, nullptr, nullptr, nullptr, nullptr, nullptr, 512, 262144);
  // 5. softmax (sums partials) -> Sc (fp32 output) + S1 = Sc - I (bf16)
  softmax_rows<<<BB * CCH, 64, 0, stream>>>(spare, sc_f, S1b);
  // 6. Mc = S1 @ F + F (bf16)
  gemm_nt<1, 0><<<dim3(8, 4, BB), 256, 0, stream>>>(
      S1b, FbT, 512, 512, 512, (size_t)CCH * CCH, (size_t)PP * CCH,
      nullptr, nullptr, Mcb, Fb, nullptr, nullptr, 1024, (size_t)CCH * PP);
  // 7. upsample Mc -> Mup (bf16) + per-channel mean
  upsample_kernel<<<BB * CCH, 256, 0, stream>>>(Mcb, Mup, mmean);
  // 8. cov partials = Xb Mup^T, split-K x4 in one dispatch -> spare
  gemm_nt<0, 2><<<dim3(4, 4, BB * 4), 256, 0, stream>>>(
      Xb, Mup, 1024, 4096, 4096, NX / BB, NX / BB,
      spare, nullptr, nullptr, nullptr, nullptr, nullptr, 512, 262144);
  // 9. combine partials -> cov (fp32 output) + L1 = Sc + cov - I (bf16)
  combine_cov<<<BB * CCH, 256, 0, stream>>>(spare, sc_f, xmean, mmean, cov_f, L1b);
  // 10. Ec = L1 @ X + x (fp32 output); fused also writes out = x*(b*Ec+x)
  if (bigws) {
    gemm_nt<4, 0><<<dim3(32, 4, BB), 256, 0, stream>>>(
        L1b, XbT, 512, 512, 512, (size_t)CCH * CCH, NX / BB,
        ec_f, out_f, nullptr, nullptr, x, beta, 4096, NX / BB);
  } else {
    gemm_nt<3, 0><<<dim3(32, 4, BB), 256, 0, stream>>>(
        L1b, XbT, 512, 512, 512, (size_t)CCH * CCH, NX / BB,
        ec_f, nullptr, nullptr, nullptr, x, nullptr, 4096, NX / BB);
    finalize_kernel<<<4096, 256, 0, stream>>>(x, ec_f, beta, out_f);
  }
}

// Round 9
// 609.605 us; speedup vs baseline: 1.2010x; 1.1457x over previous
//
#include <hip/hip_runtime.h>
#include <hip/hip_bf16.h>

typedef unsigned short u16;
typedef __attribute__((ext_vector_type(8))) short bf16x8;
typedef __attribute__((ext_vector_type(4))) float f32x4;

#define BB 16
#define CCH 512
#define HW 4096
#define PP 1024

__device__ __forceinline__ u16 f2bf(float f) {
  union { float f; unsigned u; } v; v.f = f;
  unsigned r = v.u + 0x7fffu + ((v.u >> 16) & 1u);
  return (u16)(r >> 16);
}
__device__ __forceinline__ float bf2f(u16 h) {
  union { unsigned u; float f; } v; v.u = ((unsigned)h) << 16;
  return v.f;
}

typedef __attribute__((address_space(1))) const unsigned gas_u32;
typedef __attribute__((address_space(3))) unsigned las_u32;
__device__ __forceinline__ void gl_lds16(const u16* g, u16* l) {
  // 16B per lane, dest = wave-uniform base + lane*16 (linear)
  __builtin_amdgcn_global_load_lds((gas_u32*)g, (las_u32*)l, 16, 0, 0);
}

// ---- pool: x -> Fb (2x2 avg, bf16), XUb (adjoint-bilinear-upsample of x,
//      bf16, = X*U so that X*Mup^T == XU*Mc^T), xmean ----------------------
__global__ __launch_bounds__(256) void pool_kernel(
    const float* __restrict__ x, u16* __restrict__ Fb, u16* __restrict__ XUb,
    float* __restrict__ xmean) {
  __shared__ float row[4096];
  __shared__ float red[4];
  int bc = blockIdx.x;  // b*512 + c
  const float4* xr4 = (const float4*)(x + (size_t)bc * HW);
  float4* r4 = (float4*)row;
  int t = threadIdx.x;
#pragma unroll
  for (int s = 0; s < 4; ++s) r4[t + s * 256] = xr4[t + s * 256];
  __syncthreads();
  ushort2* f2 = (ushort2*)(Fb + (size_t)bc * PP);
  ushort2* u2 = (ushort2*)(XUb + (size_t)bc * PP);
  float sum = 0.f;
#pragma unroll
  for (int s = 0; s < 2; ++s) {
    int i = s * 256 + t;   // pooled-pair index 0..511 (cells 2i, 2i+1)
    int py = i >> 4, pxq = i & 15;
    const float* r0 = row + (2 * py) * 64;
    const float* r1 = r0 + 64;
    int c0 = 4 * pxq;
    float p0 = 0.25f * (r0[c0] + r0[c0 + 1] + r1[c0] + r1[c0 + 1]);
    float p1 = 0.25f * (r0[c0 + 2] + r0[c0 + 3] + r1[c0 + 2] + r1[c0 + 3]);
    ushort2 fp; fp.x = f2bf(p0); fp.y = f2bf(p1);
    f2[i] = fp;
    sum += p0 + p1;
    // adjoint upsample: taps rows 2py-1..2py+2, cols 4pxq-1..4pxq+4,
    // weights {.25,.75,.75,.25}, clamp-accumulate at edges.
    int ry0 = (py == 0) ? 0 : 2 * py - 1;
    int ry3 = (py == 31) ? 63 : 2 * py + 2;
    const float* ra = row + ry0 * 64;
    const float* rd = row + ry3 * 64;
    float rm[6];
#pragma unroll
    for (int k = 0; k < 6; ++k) {
      int c = 4 * pxq - 1 + k;
      c = c < 0 ? 0 : (c > 63 ? 63 : c);
      rm[k] = 0.25f * (ra[c] + rd[c]) + 0.75f * (r0[c] + r1[c]);
    }
    float xu0 = 0.25f * (rm[0] + rm[3]) + 0.75f * (rm[1] + rm[2]);
    float xu1 = 0.25f * (rm[2] + rm[5]) + 0.75f * (rm[3] + rm[4]);
    ushort2 up; up.x = f2bf(xu0); up.y = f2bf(xu1);
    u2[i] = up;
  }
#pragma unroll
  for (int o = 32; o; o >>= 1) sum += __shfl_xor(sum, o);
  if ((t & 63) == 0) red[t >> 6] = sum;
  __syncthreads();
  if (t == 0) xmean[bc] = (red[0] + red[1] + red[2] + red[3]) * (1.0f / 1024.0f);
}

// ---- transpose fp32 x [512][4096] -> bf16 XbT [4096][512], per batch ------
__global__ __launch_bounds__(256) void transpose_x_bf16(
    const float* __restrict__ in, u16* __restrict__ out) {
  __shared__ u16 t[64][65];
  int b = blockIdx.z;
  const float* ib = in + (size_t)b * CCH * HW;
  u16* ob = out + (size_t)b * HW * CCH;
  int tr = blockIdx.y * 64;  // channel tile
  int tc = blockIdx.x * 64;  // hw tile
  int tid = threadIdx.x;
#pragma unroll
  for (int s = 0; s < 4; ++s) {
    int i = tid + s * 256;          // 0..1023 float4s
    int r = i >> 4, c4 = (i & 15) * 4;
    float4 v = *(const float4*)&ib[(size_t)(tr + r) * HW + tc + c4];
    t[r][c4] = f2bf(v.x); t[r][c4 + 1] = f2bf(v.y);
    t[r][c4 + 2] = f2bf(v.z); t[r][c4 + 3] = f2bf(v.w);
  }
  __syncthreads();
#pragma unroll
  for (int s = 0; s < 2; ++s) {
    int i = tid + s * 256;
    int n = i >> 3, k8 = (i & 7) * 8;
    bf16x8 o;
#pragma unroll
    for (int j = 0; j < 8; ++j) o[j] = (short)t[k8 + j][n];
    *(bf16x8*)&ob[(size_t)(tc + n) * CCH + tr + k8] = o;
  }
}

// ---- transpose bf16 [R][C] -> [C][R], 64x64 tiles (for FbT) ---------------
__global__ __launch_bounds__(256) void transpose_bf16(
    const u16* __restrict__ in, u16* __restrict__ out, int R, int C) {
  __shared__ u16 t[64][65];
  size_t bo = (size_t)blockIdx.z * R * C;
  int tr = blockIdx.y * 64, tc = blockIdx.x * 64;
  int tid = threadIdx.x;
#pragma unroll
  for (int s = 0; s < 2; ++s) {
    int i = tid + s * 256;
    int r = i >> 3, c8 = (i & 7) * 8;
    bf16x8 v = *(const bf16x8*)&in[bo + (size_t)(tr + r) * C + tc + c8];
#pragma unroll
    for (int j = 0; j < 8; ++j) t[r][c8 + j] = (u16)v[j];
  }
  __syncthreads();
#pragma unroll
  for (int s = 0; s < 2; ++s) {
    int i = tid + s * 256;
    int n = i >> 3, k8 = (i & 7) * 8;
    bf16x8 o;
#pragma unroll
    for (int j = 0; j < 8; ++j) o[j] = (short)t[k8 + j][n];
    *(bf16x8*)&out[bo + (size_t)(tc + n) * R + tr + k8] = o;
  }
}

// ---- softmax over rows; input = 2 gram partials; out Sc + (Sc-I) bf16 -----
__global__ void softmax_rows(const float* __restrict__ P, float* __restrict__ Sc,
                             u16* __restrict__ S1b) {
  size_t row = blockIdx.x;  // b*512 + c
  int z = (int)(row >> 9);
  const float* p0 = P + ((size_t)z * 2) * 262144 + (size_t)(row & 511) * 512;
  const float* p1 = p0 + 262144;
  float* g = Sc + row * 512;
  int lane = threadIdx.x;  // 64
  float v[8];
  float mx = -3.4e38f;
#pragma unroll
  for (int i = 0; i < 8; ++i) {
    int d = lane + i * 64;
    v[i] = p0[d] + p1[d];
    mx = fmaxf(mx, v[i]);
  }
#pragma unroll
  for (int o = 32; o; o >>= 1) mx = fmaxf(mx, __shfl_xor(mx, o));
  float s = 0.f;
#pragma unroll
  for (int i = 0; i < 8; ++i) { v[i] = expf(v[i] - mx); s += v[i]; }
#pragma unroll
  for (int o = 32; o; o >>= 1) s += __shfl_xor(s, o);
  float inv = 1.0f / s;
  int c = (int)(row & 511);
#pragma unroll
  for (int i = 0; i < 8; ++i) {
    int d = lane + i * 64;
    float sc = v[i] * inv;
    g[d] = sc;
    S1b[row * 512 + d] = f2bf(sc - (d == c ? 1.0f : 0.0f));
  }
}

// ---- row-mean of Mc over pooled grid (== mean of Mc_up, exactly) ----------
__global__ void mc_rowmean(const u16* __restrict__ Mcb, float* __restrict__ mmean) {
  int row = blockIdx.x;  // b*512 + d
  const bf16x8* src = (const bf16x8*)(Mcb + (size_t)row * PP);
  int lane = threadIdx.x;  // 64
  bf16x8 v0 = src[lane], v1 = src[lane + 64];
  float s = 0.f;
#pragma unroll
  for (int j = 0; j < 8; ++j) s += bf2f((u16)v0[j]) + bf2f((u16)v1[j]);
#pragma unroll
  for (int o = 32; o; o >>= 1) s += __shfl_xor(s, o);
  if (lane == 0) mmean[row] = s * (1.0f / 1024.0f);
}

// ---- NT bf16 GEMM, 128x128 tile, BK=32, 4 waves, global_load_lds ----------
// C[m][n] = sum_k A[m][k]*B[n][k], fp32 accum. LOGSPLIT: split-K folded into
// blockIdx.z (zi = batch<<LOGSPLIT | split); partial outputs indexed by zi.
// MODE 0: partial fp32 store. MODE 1: Mc = acc + F (bf16).
// MODE 3: Ec = acc + x (fp32). MODE 4: ec = acc + x; out = x*(beta*ec+x).
template <int MODE, int LOGSPLIT>
__global__ __launch_bounds__(256) void gemm_nt(
    const u16* __restrict__ A, const u16* __restrict__ B, int K, int lda, int ldb,
    size_t aStride, size_t bStride,
    float* __restrict__ outF, float* __restrict__ out2F, u16* __restrict__ outB,
    const u16* __restrict__ addB, const float* __restrict__ addF,
    const float* __restrict__ bp, int ldo, size_t oStride) {
  __shared__ u16 As[128 * 32];
  __shared__ u16 Bs[128 * 32];
  const int tid = threadIdx.x;
  const int lane = tid & 63, wave = tid >> 6;
  const int wr = wave >> 1, wc = wave & 1;
  const int zi = blockIdx.z;
  const int sp = zi & ((1 << LOGSPLIT) - 1);
  const int z = zi >> LOGSPLIT;
  const u16* Ab = A + (size_t)z * aStride + (size_t)sp * K + (size_t)(blockIdx.y * 128) * lda;
  const u16* Bb = B + (size_t)z * bStride + (size_t)sp * K + (size_t)(blockIdx.x * 128) * ldb;

  f32x4 acc[4][4] = {};

  const int stRow = lane >> 2;
  const int stCol = (lane & 3) * 8;
  u16* aL0 = As + (wave * 16) * 32;
  u16* aL1 = As + ((wave + 4) * 16) * 32;
  u16* bL0 = Bs + (wave * 16) * 32;
  u16* bL1 = Bs + ((wave + 4) * 16) * 32;
  const int fr = lane & 15, kq = lane >> 4;

  for (int k0 = 0; k0 < K; k0 += 32) {
    __syncthreads();
    gl_lds16(Ab + (size_t)(wave * 16 + stRow) * lda + k0 + stCol, aL0);
    gl_lds16(Ab + (size_t)((wave + 4) * 16 + stRow) * lda + k0 + stCol, aL1);
    gl_lds16(Bb + (size_t)(wave * 16 + stRow) * ldb + k0 + stCol, bL0);
    gl_lds16(Bb + (size_t)((wave + 4) * 16 + stRow) * ldb + k0 + stCol, bL1);
    __syncthreads();
    bf16x8 af[4], bfr[4];
#pragma unroll
    for (int m = 0; m < 4; ++m)
      af[m] = *(const bf16x8*)&As[(wr * 64 + m * 16 + fr) * 32 + kq * 8];
#pragma unroll
    for (int n = 0; n < 4; ++n)
      bfr[n] = *(const bf16x8*)&Bs[(wc * 64 + n * 16 + fr) * 32 + kq * 8];
#pragma unroll
    for (int m = 0; m < 4; ++m)
#pragma unroll
      for (int n = 0; n < 4; ++n)
        acc[m][n] = __builtin_amdgcn_mfma_f32_16x16x32_bf16(af[m], bfr[n], acc[m][n], 0, 0, 0);
  }

  float betaV = 0.f;
  if constexpr (MODE == 4) betaV = bp[0];
  const int cq = lane >> 4, cr = lane & 15;
#pragma unroll
  for (int m = 0; m < 4; ++m) {
#pragma unroll
    for (int n = 0; n < 4; ++n) {
      int row0 = blockIdx.y * 128 + wr * 64 + m * 16 + cq * 4;
      int col  = blockIdx.x * 128 + wc * 64 + n * 16 + cr;
#pragma unroll
      for (int j = 0; j < 4; ++j) {
        int r = row0 + j;
        float val = acc[m][n][j];
        size_t idx = oStride * (size_t)zi + (size_t)r * ldo + col;
        if constexpr (MODE == 0) {
          outF[idx] = val;
        } else if constexpr (MODE == 1) {
          outB[idx] = f2bf(val + bf2f(addB[idx]));
        } else if constexpr (MODE == 3) {
          outF[idx] = val + addF[idx];
        } else if constexpr (MODE == 4) {
          float xv = addF[idx];
          float ec = val + xv;
          outF[idx] = ec;
          out2F[idx] = xv * (betaV * ec + xv);
        }
      }
    }
  }
}

// ---- combine: cov = (p0+p1)/4096 - xm*mm ; L1 = Sc + cov - I --------------
__global__ __launch_bounds__(256) void combine_cov(
    const float* __restrict__ parts, const float* __restrict__ sc,
    const float* __restrict__ xm, const float* __restrict__ mm,
    float* __restrict__ cov, u16* __restrict__ L1b) {
  int row = blockIdx.x;  // z*512 + r
  int z = row >> 9, r = row & 511;
  size_t base = (size_t)z * 262144 + (size_t)r * 512;
  size_t pz = (size_t)z * 2 * 262144 + (size_t)r * 512;
  float xmr = xm[row];
#pragma unroll
  for (int j = 0; j < 2; ++j) {
    int c = threadIdx.x + j * 256;
    float s = parts[pz + c] + parts[pz + 262144 + c];
    float cv = s * (1.0f / 4096.0f) - xmr * mm[z * 512 + c];
    cov[base + c] = cv;
    L1b[base + c] = f2bf(sc[base + c] + cv - (r == c ? 1.0f : 0.0f));
  }
}

// ---- out = x * (beta*Ec + x)  (fallback path only) ------------------------
__global__ void finalize_kernel(const float* __restrict__ x, const float* __restrict__ ec,
                                const float* __restrict__ beta, float* __restrict__ out) {
  float b = beta[0];
  size_t i = (size_t)blockIdx.x * 256 + threadIdx.x;
  size_t stride = (size_t)gridDim.x * 256;
  const float4* x4 = (const float4*)x;
  const float4* e4 = (const float4*)ec;
  float4* o4 = (float4*)out;
  size_t n4 = (size_t)BB * CCH * HW / 4;
  for (size_t p = i; p < n4; p += stride) {
    float4 xv = x4[p], ev = e4[p];
    float4 ov;
    ov.x = xv.x * (b * ev.x + xv.x);
    ov.y = xv.y * (b * ev.y + xv.y);
    ov.z = xv.z * (b * ev.z + xv.z);
    ov.w = xv.w * (b * ev.w + xv.w);
    o4[p] = ov;
  }
}

extern "C" void kernel_launch(void* const* d_in, const int* in_sizes, int n_in,
                              void* d_out, int out_size, void* d_ws, size_t ws_size,
                              hipStream_t stream) {
  const float* x = (const float*)d_in[0];
  const float* beta = (const float*)d_in[1];

  const size_t NX = (size_t)BB * CCH * HW;     // 33,554,432
  const size_t NCOV = (size_t)BB * CCH * CCH;  // 4,194,304
  const size_t MB = 1u << 20;

  float* out_f = (float*)d_out;
  float* cov_f = out_f + NX;
  float* sc_f  = cov_f + NCOV;
  float* ec_f  = sc_f + NCOV;

  // spare partial buffer aliased into ec-slot (dead before Ec GEMM writes it)
  float* spare = ec_f;  // up to 32MB of fp32 partials

  char* w = (char*)d_ws;
  u16* Fb   = (u16*)(w);             // [b][512][1024] pooled
  u16* FbT  = (u16*)(w + 16 * MB);   // [b][1024][512]
  u16* Mcb  = (u16*)(w + 32 * MB);   // [b][512][1024]
  u16* XUb  = (u16*)(w + 48 * MB);   // [b][512][1024] adjoint-upsampled x
  u16* S1b  = (u16*)(w + 64 * MB);   // [b][512][512]  Sc - I
  u16* L1b  = (u16*)(w + 72 * MB);   // [b][512][512]  Lc - I
  float* xmean = (float*)(w + 80 * MB);
  float* mmean = (float*)(w + 80 * MB + 65536);
  const size_t WS_BASE = 81 * MB;
  const bool bigws = ws_size >= WS_BASE + 64 * MB;  // + XbT (64MB)

  u16* XbT = bigws ? (u16*)(w + WS_BASE) : (u16*)d_out;  // [b][4096][512]

  // 1. pool: Fb, XUb, xmean
  pool_kernel<<<BB * CCH, 256, 0, stream>>>(x, Fb, XUb, xmean);
  // 2. XbT directly from fp32 x (x likely still L3-resident)
  transpose_x_bf16<<<dim3(64, 8, BB), 256, 0, stream>>>(x, XbT);
  // 3. FbT
  transpose_bf16<<<dim3(16, 8, BB), 256, 0, stream>>>(Fb, FbT, 512, 1024);
  // 4. Gram partials = F F^T (split-K x2)
  gemm_nt<0, 1><<<dim3(4, 4, BB * 2), 256, 0, stream>>>(
      Fb, Fb, 512, 1024, 1024, (size_t)CCH * PP, (size_t)CCH * PP,
      spare, nullptr, nullptr, nullptr, nullptr, nullptr, 512, 262144);
  // 5. softmax -> Sc (fp32 output) + S1 = Sc - I (bf16)
  softmax_rows<<<BB * CCH, 64, 0, stream>>>(spare, sc_f, S1b);
  // 6. Mc = S1 @ F + F (bf16)
  gemm_nt<1, 0><<<dim3(8, 4, BB), 256, 0, stream>>>(
      S1b, FbT, 512, 512, 512, (size_t)CCH * CCH, (size_t)PP * CCH,
      nullptr, nullptr, Mcb, Fb, nullptr, nullptr, 1024, (size_t)CCH * PP);
  // 7. mmean = row-mean of Mc (== mean of upsampled Mc, exact identity)
  mc_rowmean<<<BB * CCH, 64, 0, stream>>>(Mcb, mmean);
  // 8. cov partials = XU Mc^T (split-K x2; K=1024 via adjoint-upsample trick)
  gemm_nt<0, 1><<<dim3(4, 4, BB * 2), 256, 0, stream>>>(
      XUb, Mcb, 512, 1024, 1024, (size_t)CCH * PP, (size_t)CCH * PP,
      spare, nullptr, nullptr, nullptr, nullptr, nullptr, 512, 262144);
  // 9. combine -> cov (fp32 output) + L1 = Sc + cov - I (bf16)
  combine_cov<<<BB * CCH, 256, 0, stream>>>(spare, sc_f, xmean, mmean, cov_f, L1b);
  // 10. Ec = L1 @ X + x (fp32 output); fused finalize writes out = x*(b*Ec+x)
  if (bigws) {
    gemm_nt<4, 0><<<dim3(32, 4, BB), 256, 0, stream>>>(
        L1b, XbT, 512, 512, 512, (size_t)CCH * CCH, (size_t)HW * CCH,
        ec_f, out_f, nullptr, nullptr, x, beta, 4096, NX / BB);
  } else {
    gemm_nt<3, 0><<<dim3(32, 4, BB), 256, 0, stream>>>(
        L1b, XbT, 512, 512, 512, (size_t)CCH * CCH, NX / BB,
        ec_f, nullptr, nullptr, nullptr, x, nullptr, 4096, NX / BB);
    finalize_kernel<<<4096, 256, 0, stream>>>(x, ec_f, beta, out_f);
  }
}